// Round 1
// baseline (237.790 us; speedup 1.0000x reference)
//
#include <hip/hip_runtime.h>
#include <math.h>

typedef unsigned short u16;
typedef unsigned int u32;
typedef __bf16 bf16x8 __attribute__((ext_vector_type(8)));
typedef float f32x4 __attribute__((ext_vector_type(4)));

// ---------- helpers ----------
__device__ __forceinline__ u16 f2bf(float f) {
  union { float f; u32 u; } v; v.f = f;
  u32 r = v.u + 0x7fffu + ((v.u >> 16) & 1u);
  return (u16)(r >> 16);
}

// async global->LDS, 16B per lane. LDS dest must be wave-uniform base; HW adds lane*16.
__device__ __forceinline__ void gld16(const void* g, void* s) {
  __builtin_amdgcn_global_load_lds(
      reinterpret_cast<__attribute__((address_space(1))) u32*>((size_t)g),
      reinterpret_cast<__attribute__((address_space(3))) u32*>((u32)(size_t)s),
      16, 0, 0);
}

// ---------- prep: fp32 -> bf16 (vectorized) ----------
__global__ __launch_bounds__(256) void convk(const float* __restrict__ src,
                                             u16* __restrict__ dst, int n4) {
  int i = blockIdx.x * 256 + threadIdx.x;
  if (i >= n4) return;
  float4 v = ((const float4*)src)[i];
  uint2 o;
  o.x = (u32)f2bf(v.x) | ((u32)f2bf(v.y) << 16);
  o.y = (u32)f2bf(v.z) | ((u32)f2bf(v.w) << 16);
  ((uint2*)dst)[i] = o;
}

// ---------- prep: relative-position bucket LUT: lut[h][dix], dix = (s-t)+2048 ----------
__global__ __launch_bounds__(256) void lutk(const float* __restrict__ rel_emb,
                                            float* __restrict__ lut) {
  int dix = blockIdx.x * 256 + threadIdx.x;
  if (dix >= 4096) return;
  int rp = dix - 2048;                 // rp = s - t
  int bucket = (rp > 0) ? 16 : 0;
  int rpa = rp < 0 ? -rp : rp;
  if (rpa < 8) {
    bucket += rpa;
  } else {
    // 8 + trunc( log(rpa/8)/log(16) * 8 ), clamped to 15
    int large = 8 + (int)(logf((float)rpa * 0.125f) * (8.0f / 2.772588722239781f));
    bucket += (large < 15) ? large : 15;
  }
#pragma unroll
  for (int h = 0; h < 16; ++h) lut[h * 4096 + dix] = rel_emb[bucket * 16 + h];
}

// ---------- prep: gate_a_1[b,h,t] (exact fp32) ----------
__global__ __launch_bounds__(256) void gatek(const float* __restrict__ query,
                                             const float* __restrict__ grep_w,
                                             const float* __restrict__ grep_b,
                                             const float* __restrict__ grep_a,
                                             float* __restrict__ gate) {
  __shared__ __align__(16) float gw[8][64];
  __shared__ float gb[8];
  __shared__ float ga[16];
  int tid = threadIdx.x;
  if (tid < 128) ((float4*)&gw[0][0])[tid] = ((const float4*)grep_w)[tid];
  if (tid < 8) gb[tid] = grep_b[tid];
  if (tid < 16) ga[tid] = grep_a[tid];
  __syncthreads();
  int i = blockIdx.x * 256 + tid;          // i = ((b*16+h)*2048 + t)
  int t = i & 2047, h = (i >> 11) & 15, b = i >> 15;
  const float* x = query + ((size_t)t * 2 + b) * 1024 + h * 64;
  float acc[8] = {0, 0, 0, 0, 0, 0, 0, 0};
  for (int e4 = 0; e4 < 16; ++e4) {
    float4 xv = ((const float4*)x)[e4];
#pragma unroll
    for (int j = 0; j < 8; ++j)
      acc[j] += xv.x * gw[j][e4 * 4] + xv.y * gw[j][e4 * 4 + 1] +
                xv.z * gw[j][e4 * 4 + 2] + xv.w * gw[j][e4 * 4 + 3];
  }
  float sA = acc[0] + acc[1] + acc[2] + acc[3] + gb[0] + gb[1] + gb[2] + gb[3];
  float sB = acc[4] + acc[5] + acc[6] + acc[7] + gb[4] + gb[5] + gb[6] + gb[7];
  float gA = 1.0f / (1.0f + expf(-sA));
  float gB = 1.0f / (1.0f + expf(-sB));
  gate[i] = gA * (gB * ga[h] - 1.0f) + 2.0f;
}

// ---------- GEMM: C[m][n] = A[m][:] . W[n][:] (+bias), bf16 MFMA, 128x128 tile, BK=64 ----------
// mode 0: q -> qa[b,h,t,d] * 0.125 ; mode 1: k -> ka[b,h,t,d] ; mode 2: v -> vt[b,h,d,t]
// mode 3: out-proj -> fout[m][n] fp32
__global__ __launch_bounds__(256) void gemmk(
    const u16* __restrict__ A,
    const u16* __restrict__ W0, const u16* __restrict__ W1, const u16* __restrict__ W2,
    const float* __restrict__ b0, const float* __restrict__ b1, const float* __restrict__ b2,
    u16* __restrict__ qa, u16* __restrict__ ka, u16* __restrict__ vt,
    float* __restrict__ fout, int moBase) {
  const int mode = moBase + (int)blockIdx.z;
  const u16* W = (mode == 1) ? W1 : (mode == 2) ? W2 : W0;
  const float* bias = (mode == 1) ? b1 : (mode == 2) ? b2 : b0;

  __shared__ __align__(16) u16 As[128 * 64];   // [row][64] bf16, 8 16B-slots/row, slot^= (row&7)
  __shared__ __align__(16) u16 Bs[128 * 64];

  const int tid = threadIdx.x;
  const int l = tid & 63;
  const int w = tid >> 6;
  const int wr = w >> 1, wc = w & 1;
  const int m0 = blockIdx.y * 128, n0 = blockIdx.x * 128;
  const int li = l >> 3, ls = l & 7;

  f32x4 acc[4][4] = {};

  for (int k0 = 0; k0 < 1024; k0 += 64) {
#pragma unroll
    for (int j = 0; j < 4; ++j) {
      const int rr = (w * 4 + j) * 8 + li;      // tile row 0..127
      const int cs = ls ^ (rr & 7);             // inverse-swizzled source slot
      gld16(A + ((size_t)(m0 + rr) << 10) + k0 + cs * 8, &As[(w * 4 + j) * 512]);
      gld16(W + ((size_t)(n0 + rr) << 10) + k0 + cs * 8, &Bs[(w * 4 + j) * 512]);
    }
    __syncthreads();
#pragma unroll
    for (int ks = 0; ks < 2; ++ks) {
      bf16x8 af[4], bfr[4];
#pragma unroll
      for (int mf = 0; mf < 4; ++mf) {
        const int row = wr * 64 + mf * 16 + (l & 15);
        const int slot = (ks * 4 + (l >> 4)) ^ (row & 7);
        af[mf] = *(const bf16x8*)&As[row * 64 + slot * 8];
      }
#pragma unroll
      for (int nf = 0; nf < 4; ++nf) {
        const int row = wc * 64 + nf * 16 + (l & 15);
        const int slot = (ks * 4 + (l >> 4)) ^ (row & 7);
        bfr[nf] = *(const bf16x8*)&Bs[row * 64 + slot * 8];
      }
#pragma unroll
      for (int mf = 0; mf < 4; ++mf)
#pragma unroll
        for (int nf = 0; nf < 4; ++nf)
          acc[mf][nf] = __builtin_amdgcn_mfma_f32_16x16x32_bf16(af[mf], bfr[nf], acc[mf][nf], 0, 0, 0);
    }
    __syncthreads();
  }

#pragma unroll
  for (int mf = 0; mf < 4; ++mf)
#pragma unroll
    for (int nf = 0; nf < 4; ++nf)
#pragma unroll
      for (int r = 0; r < 4; ++r) {
        const int row = m0 + wr * 64 + mf * 16 + (l >> 4) * 4 + r;  // m = t*2+b
        const int col = n0 + wc * 64 + nf * 16 + (l & 15);          // n = h*64+d
        float v = acc[mf][nf][r] + bias[col];
        const int t = row >> 1, bb = row & 1, hh = col >> 6, d = col & 63;
        if (mode == 0) {
          v *= 0.125f;  // HD^-0.5
          qa[((((size_t)bb * 16 + hh) * 2048 + t) << 6) + d] = f2bf(v);
        } else if (mode == 1) {
          ka[((((size_t)bb * 16 + hh) * 2048 + t) << 6) + d] = f2bf(v);
        } else if (mode == 2) {
          vt[((((size_t)bb * 16 + hh) * 64 + d) << 11) + t] = f2bf(v);
        } else {
          fout[((size_t)row << 10) + col] = v;
        }
      }
}

// ---------- flash attention with gated rel-pos bias ----------
// grid (16 q-tiles, 32 bh), 256 thr = 4 waves x 32 rows; KVBLK=64; K/V direct from L2.
__global__ __launch_bounds__(256) void flashk(const u16* __restrict__ qa,
                                              const u16* __restrict__ ka,
                                              const u16* __restrict__ vt,
                                              const float* __restrict__ lutg,
                                              const float* __restrict__ gatew,
                                              u16* __restrict__ aout) {
  const int bh = blockIdx.y, h = bh & 15, b = bh >> 4;
  const int tid = threadIdx.x, l = tid & 63, w = tid >> 6;
  const int t0 = blockIdx.x * 128 + w * 32;

  __shared__ __align__(16) float lut[4096];
  __shared__ __align__(16) u16 pbuf[4][32 * 64];

  for (int i = tid; i < 1024; i += 256)
    ((float4*)lut)[i] = ((const float4*)(lutg + (size_t)h * 4096))[i];
  __syncthreads();

  const u16* Q = qa + ((size_t)bh << 11 << 6);
  const u16* K = ka + ((size_t)bh << 11 << 6);
  const u16* V = vt + ((size_t)bh << 6 << 11);
  u16* pb = &pbuf[w][0];

  bf16x8 qf[2][2];
#pragma unroll
  for (int rf = 0; rf < 2; ++rf)
#pragma unroll
    for (int ks = 0; ks < 2; ++ks)
      qf[rf][ks] = *(const bf16x8*)&Q[((size_t)(t0 + rf * 16 + (l & 15)) << 6) + ks * 32 + ((l >> 4) << 3)];

  float gate_r[2][4];
#pragma unroll
  for (int rf = 0; rf < 2; ++rf)
#pragma unroll
    for (int r = 0; r < 4; ++r)
      gate_r[rf][r] = gatew[((size_t)bh << 11) + t0 + rf * 16 + (l >> 4) * 4 + r];

  float mrow[2][4], lrow[2][4];
  f32x4 oacc[2][4] = {};
#pragma unroll
  for (int rf = 0; rf < 2; ++rf)
#pragma unroll
    for (int r = 0; r < 4; ++r) { mrow[rf][r] = -1e30f; lrow[rf][r] = 0.0f; }

  for (int s0 = 0; s0 < 2048; s0 += 64) {
    // S = Q.K^T (+bias later); C layout: row=(l>>4)*4+r, col=l&15
    f32x4 sacc[2][4] = {};
#pragma unroll
    for (int ks = 0; ks < 2; ++ks) {
      bf16x8 kf[4];
#pragma unroll
      for (int sf = 0; sf < 4; ++sf)
        kf[sf] = *(const bf16x8*)&K[((size_t)(s0 + sf * 16 + (l & 15)) << 6) + ks * 32 + ((l >> 4) << 3)];
#pragma unroll
      for (int rf = 0; rf < 2; ++rf)
#pragma unroll
        for (int sf = 0; sf < 4; ++sf)
          sacc[rf][sf] = __builtin_amdgcn_mfma_f32_16x16x32_bf16(qf[rf][ks], kf[sf], sacc[rf][sf], 0, 0, 0);
    }
    // bias + online softmax per row; P -> swizzled LDS (bf16)
#pragma unroll
    for (int rf = 0; rf < 2; ++rf)
#pragma unroll
      for (int r = 0; r < 4; ++r) {
        const int trow = t0 + rf * 16 + (l >> 4) * 4 + r;
        const float g = gate_r[rf][r];
        float smax = -1e30f;
#pragma unroll
        for (int sf = 0; sf < 4; ++sf) {
          const int scol = s0 + sf * 16 + (l & 15);
          float vv = sacc[rf][sf][r] + g * lut[scol - trow + 2048];
          sacc[rf][sf][r] = vv;
          smax = fmaxf(smax, vv);
        }
#pragma unroll
        for (int off = 8; off > 0; off >>= 1) smax = fmaxf(smax, __shfl_xor(smax, off, 64));
        const float mold = mrow[rf][r];
        const float mnew = fmaxf(mold, smax);
        const float sc = __expf(mold - mnew);
        float rs = 0.0f;
        const int prow = rf * 16 + (l >> 4) * 4 + r;
#pragma unroll
        for (int sf = 0; sf < 4; ++sf) {
          const float p = __expf(sacc[rf][sf][r] - mnew);
          const int col = sf * 16 + (l & 15);
          const int slot = (col >> 3) ^ (prow & 7);
          pb[prow * 64 + slot * 8 + (col & 7)] = f2bf(p);
          rs += p;
        }
#pragma unroll
        for (int off = 8; off > 0; off >>= 1) rs += __shfl_xor(rs, off, 64);
        lrow[rf][r] = lrow[rf][r] * sc + rs;
        mrow[rf][r] = mnew;
#pragma unroll
        for (int df = 0; df < 4; ++df) oacc[rf][df][r] *= sc;
      }
    // O += P.V   (V stored transposed [d][s] -> contiguous B-frag rows)
#pragma unroll
    for (int ks2 = 0; ks2 < 2; ++ks2) {
      bf16x8 pf[2], vf[4];
#pragma unroll
      for (int rf = 0; rf < 2; ++rf) {
        const int prow = rf * 16 + (l & 15);
        const int slot = (ks2 * 4 + (l >> 4)) ^ (prow & 7);
        pf[rf] = *(const bf16x8*)&pb[prow * 64 + slot * 8];
      }
#pragma unroll
      for (int df = 0; df < 4; ++df)
        vf[df] = *(const bf16x8*)&V[((size_t)(df * 16 + (l & 15)) << 11) + s0 + ks2 * 32 + ((l >> 4) << 3)];
#pragma unroll
      for (int rf = 0; rf < 2; ++rf)
#pragma unroll
        for (int df = 0; df < 4; ++df)
          oacc[rf][df] = __builtin_amdgcn_mfma_f32_16x16x32_bf16(pf[rf], vf[df], oacc[rf][df], 0, 0, 0);
    }
  }

#pragma unroll
  for (int rf = 0; rf < 2; ++rf)
#pragma unroll
    for (int r = 0; r < 4; ++r) {
      const float inv = 1.0f / lrow[rf][r];
      const int trow = t0 + rf * 16 + (l >> 4) * 4 + r;
#pragma unroll
      for (int df = 0; df < 4; ++df) {
        const int d = df * 16 + (l & 15);
        aout[(((size_t)trow * 2 + b) << 10) + h * 64 + d] = f2bf(oacc[rf][df][r] * inv);
      }
    }
}

// ---------- launch ----------
extern "C" void kernel_launch(void* const* d_in, const int* in_sizes, int n_in,
                              void* d_out, int out_size, void* d_ws, size_t ws_size,
                              hipStream_t stream) {
  (void)in_sizes; (void)n_in; (void)out_size; (void)ws_size;
  const float* query  = (const float*)d_in[0];
  const float* q_w    = (const float*)d_in[1];
  const float* q_b    = (const float*)d_in[2];
  const float* k_w    = (const float*)d_in[3];
  const float* k_b    = (const float*)d_in[4];
  const float* v_w    = (const float*)d_in[5];
  const float* v_b    = (const float*)d_in[6];
  const float* out_w  = (const float*)d_in[7];
  const float* out_b  = (const float*)d_in[8];
  const float* rel_emb= (const float*)d_in[9];
  const float* grep_w = (const float*)d_in[10];
  const float* grep_b = (const float*)d_in[11];
  const float* grep_a = (const float*)d_in[12];

  char* ws = (char*)d_ws;
  const size_t MB = 1ull << 20;
  u16* qbf  = (u16*)(ws + 0 * MB);      // 8MB  query bf16 (t,b,e)
  u16* wqb  = (u16*)(ws + 8 * MB);      // 2MB
  u16* wkb  = (u16*)(ws + 10 * MB);
  u16* wvb  = (u16*)(ws + 12 * MB);
  u16* wob  = (u16*)(ws + 14 * MB);
  u16* qav  = (u16*)(ws + 16 * MB);     // 8MB  [b,h,t,d]
  u16* kav  = (u16*)(ws + 24 * MB);     // 8MB  [b,h,t,d]
  u16* vtv  = (u16*)(ws + 32 * MB);     // 8MB  [b,h,d,t]
  u16* aout = (u16*)(ws + 40 * MB);     // 8MB  attn out (t,b,e) bf16
  float* lut  = (float*)(ws + 48 * MB);           // 256KB [h][4096]
  float* gate = (float*)(ws + 48 * MB + 256 * 1024); // 256KB [b,h,t]

  convk<<<dim3(4096), 256, 0, stream>>>(query, qbf, 1048576);
  convk<<<dim3(1024), 256, 0, stream>>>(q_w, wqb, 262144);
  convk<<<dim3(1024), 256, 0, stream>>>(k_w, wkb, 262144);
  convk<<<dim3(1024), 256, 0, stream>>>(v_w, wvb, 262144);
  convk<<<dim3(1024), 256, 0, stream>>>(out_w, wob, 262144);
  lutk<<<dim3(16), 256, 0, stream>>>(rel_emb, lut);
  gatek<<<dim3(256), 256, 0, stream>>>(query, grep_w, grep_b, grep_a, gate);

  gemmk<<<dim3(8, 32, 3), 256, 0, stream>>>(qbf, wqb, wkb, wvb, q_b, k_b, v_b,
                                            qav, kav, vtv, nullptr, 0);
  flashk<<<dim3(16, 32), 256, 0, stream>>>(qav, kav, vtv, lut, gate, aout);
  gemmk<<<dim3(8, 32, 1), 256, 0, stream>>>(aout, wob, nullptr, nullptr, out_b, nullptr, nullptr,
                                            nullptr, nullptr, nullptr, (float*)d_out, 3);
}

// Round 2
// 225.800 us; speedup vs baseline: 1.0531x; 1.0531x over previous
//
#include <hip/hip_runtime.h>
#include <math.h>

typedef unsigned short u16;
typedef unsigned int u32;
typedef __bf16 bf16x8 __attribute__((ext_vector_type(8)));
typedef float f32x4 __attribute__((ext_vector_type(4)));
typedef float f32x16 __attribute__((ext_vector_type(16)));

// ---------- helpers ----------
__device__ __forceinline__ u16 f2bf(float f) {
  union { float f; u32 u; } v; v.f = f;
  u32 r = v.u + 0x7fffu + ((v.u >> 16) & 1u);
  return (u16)(r >> 16);
}

__device__ __forceinline__ u32 pkbf(float a, float b) {
  u32 r;
  asm("v_cvt_pk_bf16_f32 %0, %1, %2" : "=v"(r) : "v"(a), "v"(b));
  return r;
}

// async global->LDS, 16B per lane. LDS dest must be wave-uniform base; HW adds lane*16.
__device__ __forceinline__ void gld16(const void* g, void* s) {
  __builtin_amdgcn_global_load_lds(
      reinterpret_cast<__attribute__((address_space(1))) u32*>((size_t)g),
      reinterpret_cast<__attribute__((address_space(3))) u32*>((u32)(size_t)s),
      16, 0, 0);
}

// ---------- prep: fp32 -> bf16 (vectorized) ----------
__global__ __launch_bounds__(256) void convk(const float* __restrict__ src,
                                             u16* __restrict__ dst, int n4) {
  int i = blockIdx.x * 256 + threadIdx.x;
  if (i >= n4) return;
  float4 v = ((const float4*)src)[i];
  uint2 o;
  o.x = (u32)f2bf(v.x) | ((u32)f2bf(v.y) << 16);
  o.y = (u32)f2bf(v.z) | ((u32)f2bf(v.w) << 16);
  ((uint2*)dst)[i] = o;
}

// ---------- prep: relative-position bucket LUT: lut[h][dix], dix = (s-t)+2048 ----------
__global__ __launch_bounds__(256) void lutk(const float* __restrict__ rel_emb,
                                            float* __restrict__ lut) {
  int dix = blockIdx.x * 256 + threadIdx.x;
  if (dix >= 4096) return;
  int rp = dix - 2048;                 // rp = s - t
  int bucket = (rp > 0) ? 16 : 0;
  int rpa = rp < 0 ? -rp : rp;
  if (rpa < 8) {
    bucket += rpa;
  } else {
    int large = 8 + (int)(logf((float)rpa * 0.125f) * (8.0f / 2.772588722239781f));
    bucket += (large < 15) ? large : 15;
  }
#pragma unroll
  for (int h = 0; h < 16; ++h) lut[h * 4096 + dix] = rel_emb[bucket * 16 + h];
}

// ---------- prep: gate_a_1[b,h,t] (exact fp32) ----------
__global__ __launch_bounds__(256) void gatek(const float* __restrict__ query,
                                             const float* __restrict__ grep_w,
                                             const float* __restrict__ grep_b,
                                             const float* __restrict__ grep_a,
                                             float* __restrict__ gate) {
  __shared__ __align__(16) float gw[8][64];
  __shared__ float gb[8];
  __shared__ float ga[16];
  int tid = threadIdx.x;
  if (tid < 128) ((float4*)&gw[0][0])[tid] = ((const float4*)grep_w)[tid];
  if (tid < 8) gb[tid] = grep_b[tid];
  if (tid < 16) ga[tid] = grep_a[tid];
  __syncthreads();
  int i = blockIdx.x * 256 + tid;          // i = ((b*16+h)*2048 + t)
  int t = i & 2047, h = (i >> 11) & 15, b = i >> 15;
  const float* x = query + ((size_t)t * 2 + b) * 1024 + h * 64;
  float acc[8] = {0, 0, 0, 0, 0, 0, 0, 0};
  for (int e4 = 0; e4 < 16; ++e4) {
    float4 xv = ((const float4*)x)[e4];
#pragma unroll
    for (int j = 0; j < 8; ++j)
      acc[j] += xv.x * gw[j][e4 * 4] + xv.y * gw[j][e4 * 4 + 1] +
                xv.z * gw[j][e4 * 4 + 2] + xv.w * gw[j][e4 * 4 + 3];
  }
  float sA = acc[0] + acc[1] + acc[2] + acc[3] + gb[0] + gb[1] + gb[2] + gb[3];
  float sB = acc[4] + acc[5] + acc[6] + acc[7] + gb[4] + gb[5] + gb[6] + gb[7];
  float gA = 1.0f / (1.0f + expf(-sA));
  float gB = 1.0f / (1.0f + expf(-sB));
  gate[i] = gA * (gB * ga[h] - 1.0f) + 2.0f;
}

// ---------- GEMM: C[m][n] = A[m][:] . W[n][:] (+bias), bf16 MFMA, 128x128 tile, BK=64 ----------
__global__ __launch_bounds__(256) void gemmk(
    const u16* __restrict__ A,
    const u16* __restrict__ W0, const u16* __restrict__ W1, const u16* __restrict__ W2,
    const float* __restrict__ b0, const float* __restrict__ b1, const float* __restrict__ b2,
    u16* __restrict__ qa, u16* __restrict__ ka, u16* __restrict__ vt,
    float* __restrict__ fout, int moBase) {
  const int mode = moBase + (int)blockIdx.z;
  const u16* W = (mode == 1) ? W1 : (mode == 2) ? W2 : W0;
  const float* bias = (mode == 1) ? b1 : (mode == 2) ? b2 : b0;

  __shared__ __align__(16) u16 As[128 * 64];   // [row][64] bf16, 8 16B-slots/row, slot^=(row&7)
  __shared__ __align__(16) u16 Bs[128 * 64];

  const int tid = threadIdx.x;
  const int l = tid & 63;
  const int w = tid >> 6;
  const int wr = w >> 1, wc = w & 1;
  const int m0 = blockIdx.y * 128, n0 = blockIdx.x * 128;
  const int li = l >> 3, ls = l & 7;

  f32x4 acc[4][4] = {};

  for (int k0 = 0; k0 < 1024; k0 += 64) {
#pragma unroll
    for (int j = 0; j < 4; ++j) {
      const int rr = (w * 4 + j) * 8 + li;
      const int cs = ls ^ (rr & 7);
      gld16(A + ((size_t)(m0 + rr) << 10) + k0 + cs * 8, &As[(w * 4 + j) * 512]);
      gld16(W + ((size_t)(n0 + rr) << 10) + k0 + cs * 8, &Bs[(w * 4 + j) * 512]);
    }
    __syncthreads();
#pragma unroll
    for (int ks = 0; ks < 2; ++ks) {
      bf16x8 af[4], bfr[4];
#pragma unroll
      for (int mf = 0; mf < 4; ++mf) {
        const int row = wr * 64 + mf * 16 + (l & 15);
        const int slot = (ks * 4 + (l >> 4)) ^ (row & 7);
        af[mf] = *(const bf16x8*)&As[row * 64 + slot * 8];
      }
#pragma unroll
      for (int nf = 0; nf < 4; ++nf) {
        const int row = wc * 64 + nf * 16 + (l & 15);
        const int slot = (ks * 4 + (l >> 4)) ^ (row & 7);
        bfr[nf] = *(const bf16x8*)&Bs[row * 64 + slot * 8];
      }
#pragma unroll
      for (int mf = 0; mf < 4; ++mf)
#pragma unroll
        for (int nf = 0; nf < 4; ++nf)
          acc[mf][nf] = __builtin_amdgcn_mfma_f32_16x16x32_bf16(af[mf], bfr[nf], acc[mf][nf], 0, 0, 0);
    }
    __syncthreads();
  }

#pragma unroll
  for (int mf = 0; mf < 4; ++mf)
#pragma unroll
    for (int nf = 0; nf < 4; ++nf)
#pragma unroll
      for (int r = 0; r < 4; ++r) {
        const int row = m0 + wr * 64 + mf * 16 + (l >> 4) * 4 + r;  // m = t*2+b
        const int col = n0 + wc * 64 + nf * 16 + (l & 15);          // n = h*64+d
        float v = acc[mf][nf][r] + bias[col];
        const int t = row >> 1, bb = row & 1, hh = col >> 6, d = col & 63;
        if (mode == 0) {
          v *= 0.125f;  // HD^-0.5
          qa[((((size_t)bb * 16 + hh) * 2048 + t) << 6) + d] = f2bf(v);
        } else if (mode == 1) {
          ka[((((size_t)bb * 16 + hh) * 2048 + t) << 6) + d] = f2bf(v);
        } else if (mode == 2) {
          vt[((((size_t)bb * 16 + hh) * 64 + d) << 11) + t] = f2bf(v);
        } else {
          fout[((size_t)row << 10) + col] = v;
        }
      }
}

// ---------- flash attention, swapped-QK^T 32x32 structure ----------
// Each wave owns 32 q-rows; per KV-32 step: S^T = mfma(K,Q) -> lane holds 16 P-vals
// of q-row (lane&31); lane-local softmax + 1 shfl; cvt_pk+exchange -> PV B-frag.
// grid: 512 linear blocks, bijective XCD swizzle (4 heads per XCD -> K/V L2-fit).
__global__ __launch_bounds__(256) void flashk(const u16* __restrict__ qa,
                                              const u16* __restrict__ ka,
                                              const u16* __restrict__ vt,
                                              const float* __restrict__ lutg,
                                              const float* __restrict__ gatew,
                                              u16* __restrict__ aout) {
  const int B = blockIdx.x;
  const int xcd = B & 7, j = B >> 3;
  const int bh = xcd * 4 + (j >> 4);       // 4 heads per XCD
  const int qt = j & 15;
  const int h = bh & 15, b = bh >> 4;
  const int tid = threadIdx.x, l = tid & 63, w = tid >> 6;
  const int hi = l >> 5, q = l & 31;
  const int qg = qt * 128 + w * 32 + q;    // global q row

  __shared__ __align__(16) float lut[4096];
  for (int i = tid; i < 1024; i += 256)
    ((float4*)lut)[i] = ((const float4*)(lutg + (size_t)h * 4096))[i];
  __syncthreads();

  const u16* Q = qa + ((size_t)bh << 17);
  const u16* K = ka + ((size_t)bh << 17);
  const u16* V = vt + ((size_t)bh << 17);

  // Q B-frags: lane n=q, k-dim = mk*16 + hi*8 + j
  bf16x8 qf[4];
#pragma unroll
  for (int mk = 0; mk < 4; ++mk)
    qf[mk] = *(const bf16x8*)&Q[((size_t)qg << 6) + mk * 16 + hi * 8];

  const float g = gatew[((size_t)bh << 11) + qg];

  float m_run = -3e38f, l_run = 0.0f;
  f32x16 oacc[2] = {};

  for (int s0 = 0; s0 < 2048; s0 += 32) {
    // S^T tile: C[k_local][q], k_local = (reg&3)+8*(reg>>2)+4*hi
    f32x16 s = {};
#pragma unroll
    for (int mk = 0; mk < 4; ++mk) {
      bf16x8 kf = *(const bf16x8*)&K[((size_t)(s0 + q) << 6) + mk * 16 + hi * 8];
      s = __builtin_amdgcn_mfma_f32_32x32x16_bf16(kf, qf[mk], s, 0, 0, 0);
    }
    // bias + row max (lane-local + 1 cross-half shfl)
    const int ibase = s0 - qg + 2048 + 4 * hi;
    float mx = -3e38f;
#pragma unroll
    for (int reg = 0; reg < 16; ++reg) {
      const int kloc = (reg & 3) + 8 * (reg >> 2);   // + 4*hi folded in ibase
      const float v = s[reg] + g * lut[ibase + kloc];
      s[reg] = v;
      mx = fmaxf(mx, v);
    }
    mx = fmaxf(mx, __shfl_xor(mx, 32, 64));
    // defer-max (T13): rescale only when max grew by > 8
    if (!__all(mx - m_run <= 8.0f)) {
      const float mnew = fmaxf(m_run, mx);
      const float sc = __expf(m_run - mnew);
      l_run *= sc;
#pragma unroll
      for (int r = 0; r < 16; ++r) { oacc[0][r] *= sc; oacc[1][r] *= sc; }
      m_run = mnew;
    }
    // P = exp(S - m), row sum
    float rsum = 0.0f;
#pragma unroll
    for (int reg = 0; reg < 16; ++reg) {
      const float p = __expf(s[reg] - m_run);
      s[reg] = p;
      rsum += p;
    }
    rsum += __shfl_xor(rsum, 32, 64);
    l_run += rsum;
    // pack P -> PV B-frags (T12): per k-half, own-pair pk + 1 cross-half exchange
    bf16x8 pa[2];
#pragma unroll
    for (int kh = 0; kh < 2; ++kh) {
      const int rb = kh * 8;
      const u32 X0 = pkbf(s[rb + 0], s[rb + 1]);
      const u32 X1 = pkbf(s[rb + 2], s[rb + 3]);
      const u32 Y0 = pkbf(s[rb + 4], s[rb + 5]);
      const u32 Y1 = pkbf(s[rb + 6], s[rb + 7]);
      const u32 E0 = hi ? X0 : Y0;
      const u32 E1 = hi ? X1 : Y1;
      const u32 Ep0 = (u32)__shfl_xor((int)E0, 32, 64);
      const u32 Ep1 = (u32)__shfl_xor((int)E1, 32, 64);
      union { u32 wds[4]; bf16x8 v; } pu;
      pu.wds[0] = hi ? Ep0 : X0;
      pu.wds[1] = hi ? Ep1 : X1;
      pu.wds[2] = hi ? Y0 : Ep0;
      pu.wds[3] = hi ? Y1 : Ep1;
      pa[kh] = pu.v;
    }
    // O^T += V^T . P : A-frag = V^T[d][k] (vt is [d][t], contiguous in k)
#pragma unroll
    for (int dt = 0; dt < 2; ++dt)
#pragma unroll
      for (int kh = 0; kh < 2; ++kh) {
        bf16x8 vf = *(const bf16x8*)&V[((size_t)(dt * 32 + q) << 11) + s0 + kh * 16 + hi * 8];
        oacc[dt] = __builtin_amdgcn_mfma_f32_32x32x16_bf16(vf, pa[kh], oacc[dt], 0, 0, 0);
      }
  }

  // epilogue: O[q][d] = oacc/l_run ; d = dt*32 + gph*8 + hi*4 + r
  const float inv = 1.0f / l_run;
#pragma unroll
  for (int dt = 0; dt < 2; ++dt)
#pragma unroll
    for (int gph = 0; gph < 4; ++gph) {
      const int d0 = dt * 32 + gph * 8 + hi * 4;
      uint2 st;
      st.x = pkbf(oacc[dt][gph * 4 + 0] * inv, oacc[dt][gph * 4 + 1] * inv);
      st.y = pkbf(oacc[dt][gph * 4 + 2] * inv, oacc[dt][gph * 4 + 3] * inv);
      *(uint2*)&aout[(((size_t)qg * 2 + b) << 10) + h * 64 + d0] = st;
    }
}

// ---------- launch ----------
extern "C" void kernel_launch(void* const* d_in, const int* in_sizes, int n_in,
                              void* d_out, int out_size, void* d_ws, size_t ws_size,
                              hipStream_t stream) {
  (void)in_sizes; (void)n_in; (void)out_size; (void)ws_size;
  const float* query  = (const float*)d_in[0];
  const float* q_w    = (const float*)d_in[1];
  const float* q_b    = (const float*)d_in[2];
  const float* k_w    = (const float*)d_in[3];
  const float* k_b    = (const float*)d_in[4];
  const float* v_w    = (const float*)d_in[5];
  const float* v_b    = (const float*)d_in[6];
  const float* out_w  = (const float*)d_in[7];
  const float* out_b  = (const float*)d_in[8];
  const float* rel_emb= (const float*)d_in[9];
  const float* grep_w = (const float*)d_in[10];
  const float* grep_b = (const float*)d_in[11];
  const float* grep_a = (const float*)d_in[12];

  char* ws = (char*)d_ws;
  const size_t MB = 1ull << 20;
  u16* qbf  = (u16*)(ws + 0 * MB);      // 8MB  query bf16 (t,b,e)
  u16* wqb  = (u16*)(ws + 8 * MB);      // 2MB
  u16* wkb  = (u16*)(ws + 10 * MB);
  u16* wvb  = (u16*)(ws + 12 * MB);
  u16* wob  = (u16*)(ws + 14 * MB);
  u16* qav  = (u16*)(ws + 16 * MB);     // 8MB  [b,h,t,d]
  u16* kav  = (u16*)(ws + 24 * MB);     // 8MB  [b,h,t,d]
  u16* vtv  = (u16*)(ws + 32 * MB);     // 8MB  [b,h,d,t]
  u16* aout = (u16*)(ws + 40 * MB);     // 8MB  attn out (t,b,e) bf16
  float* lut  = (float*)(ws + 48 * MB);              // 256KB [h][4096]
  float* gate = (float*)(ws + 48 * MB + 256 * 1024); // 256KB [b,h,t]

  convk<<<dim3(4096), 256, 0, stream>>>(query, qbf, 1048576);
  convk<<<dim3(1024), 256, 0, stream>>>(q_w, wqb, 262144);
  convk<<<dim3(1024), 256, 0, stream>>>(k_w, wkb, 262144);
  convk<<<dim3(1024), 256, 0, stream>>>(v_w, wvb, 262144);
  convk<<<dim3(1024), 256, 0, stream>>>(out_w, wob, 262144);
  lutk<<<dim3(16), 256, 0, stream>>>(rel_emb, lut);
  gatek<<<dim3(256), 256, 0, stream>>>(query, grep_w, grep_b, grep_a, gate);

  gemmk<<<dim3(8, 32, 3), 256, 0, stream>>>(qbf, wqb, wkb, wvb, q_b, k_b, v_b,
                                            qav, kav, vtv, nullptr, 0);
  flashk<<<dim3(512), 256, 0, stream>>>(qav, kav, vtv, lut, gate, aout);
  gemmk<<<dim3(8, 32, 1), 256, 0, stream>>>(aout, wob, nullptr, nullptr, out_b, nullptr, nullptr,
                                            nullptr, nullptr, nullptr, (float*)d_out, 3);
}